// Round 1
// baseline (374.863 us; speedup 1.0000x reference)
//
#include <hip/hip_runtime.h>
#include <math.h>

#define QMAX 127.0f
#define CIN 32
#define CR 8
#define HW 16384                 // 128*128
#define BATCH 64
#define NPIX (BATCH*HW)          // 1,048,576 pixels
#define NQUAD (NPIX/4)           // 262,144 pixel-quads
#define NX (BATCH*CIN*HW)        // 33,554,432 x elements
#define COOP_BLOCKS (NQUAD/256)  // 1024 blocks -> exactly 1 quad per thread

// ws layout: wsu[0]=amax_x bits, wsu[1]=amax_h bits, wsu[2]=barrier count, wsu[3]=barrier gen;
// h buffer (fallback only) at wsf+64
#define H_OFF 64
#define WS_NEEDED ((size_t)(H_OFF + (size_t)NPIX * CR) * 4)

__device__ __forceinline__ float fq(float v, float inv_scale, float scale) {
    return rintf(fminf(fmaxf(v * inv_scale, -QMAX), QMAX)) * scale;  // round-half-even
}
__device__ __forceinline__ float sigmoidf_(float v) {
    return __builtin_amdgcn_rcpf(1.0f + __expf(-v));   // v_rcp_f32: ~1ulp, fine vs 5.5e-2 thr
}

// Minimal grid barrier: agent-scope atomics only, NO cache flush/invalidate.
// Safe here because the only cross-block data (wsu[0], wsu[1]) are themselves
// device-scope atomics; h stays in registers across the barrier.
// cnt/gen must be zeroed before launch (covered by the 16-B memset).
__device__ __forceinline__ void grid_bar(unsigned int* __restrict__ cnt,
                                         unsigned int* __restrict__ gen,
                                         unsigned int nb) {
    __syncthreads();
    if (threadIdx.x == 0) {
        unsigned int g = __hip_atomic_load(gen, __ATOMIC_RELAXED, __HIP_MEMORY_SCOPE_AGENT);
        unsigned int a = __hip_atomic_fetch_add(cnt, 1u, __ATOMIC_ACQ_REL, __HIP_MEMORY_SCOPE_AGENT);
        if (a == nb - 1u) {
            // last arriver: reset counter, then release the generation
            __hip_atomic_store(cnt, 0u, __ATOMIC_RELAXED, __HIP_MEMORY_SCOPE_AGENT);
            __hip_atomic_fetch_add(gen, 1u, __ATOMIC_RELEASE, __HIP_MEMORY_SCOPE_AGENT);
        } else {
            while (__hip_atomic_load(gen, __ATOMIC_RELAXED, __HIP_MEMORY_SCOPE_AGENT) == g)
                __builtin_amdgcn_s_sleep(1);
            __builtin_amdgcn_fence(__ATOMIC_ACQUIRE, "agent");
        }
    }
    __syncthreads();
}

// ================= Cooperative fused kernel =================
// grid = 1024 blocks x 256 thr; __launch_bounds__(256,4) caps VGPR<=128 -> 4 blocks/CU co-resident.
__global__ __launch_bounds__(256, 4) void se_fused(const float* __restrict__ x,
                                                   const float* __restrict__ identity,
                                                   const float* __restrict__ wr,
                                                   const float* __restrict__ br,
                                                   const float* __restrict__ we,
                                                   const float* __restrict__ be,
                                                   unsigned int* __restrict__ wsu,
                                                   float* __restrict__ out) {
    int t = threadIdx.x;
    __shared__ float wqr[CR * CIN], wqe[CIN * CR], bsh[CR], besh[CIN], amr[CR], ame[CIN];
    __shared__ float red[4];

    // ---- weight quantization (per-block, tiny) ----
    if (t < CR) {
        float mm = 0.f;
        for (int c = 0; c < CIN; c++) mm = fmaxf(mm, fabsf(wr[t * CIN + c]));
        amr[t] = fmaxf(mm, 1e-12f);
        bsh[t] = br[t];
    }
    if (t >= 64 && t < 64 + CIN) {
        int r = t - 64;
        float mm = 0.f;
        for (int c = 0; c < CR; c++) mm = fmaxf(mm, fabsf(we[r * CR + c]));
        ame[r] = fmaxf(mm, 1e-12f);
        besh[r] = be[r];
    }
    __syncthreads();
    {
        float a1 = amr[t >> 5];
        wqr[t] = fq(wr[t], QMAX / a1, a1 * (1.f / QMAX));
        float a2 = ame[t >> 3];
        wqe[t] = fq(we[t], QMAX / a2, a2 * (1.f / QMAX));
    }
    __syncthreads();

    const int tid = blockIdx.x * 256 + t;

    // ---- phase 1: global max|x| (32 float4 per thread, grid covers NX exactly) ----
    {
        const float4* x4 = (const float4*)x;
        float m = 0.f;
#pragma unroll 8
        for (int i = 0; i < 32; i++) {
            float4 v = x4[tid + i * NQUAD];
            m = fmaxf(m, fmaxf(fmaxf(fabsf(v.x), fabsf(v.y)), fmaxf(fabsf(v.z), fabsf(v.w))));
        }
#pragma unroll
        for (int off = 32; off > 0; off >>= 1) m = fmaxf(m, __shfl_xor(m, off, 64));
        if ((t & 63) == 0) red[t >> 6] = m;
        __syncthreads();
        if (t == 0) {
            m = fmaxf(fmaxf(red[0], red[1]), fmaxf(red[2], red[3]));
            atomicMax(&wsu[0], __float_as_uint(m));   // values >=0: uint order == float order
        }
    }
    grid_bar(&wsu[2], &wsu[3], COOP_BLOCKS);

    // ---- phase 2: h = SiLU(conv_reduce(quant(x))) kept in registers; global max|h| ----
    float a_amax = fmaxf(__uint_as_float(
        __hip_atomic_load(&wsu[0], __ATOMIC_ACQUIRE, __HIP_MEMORY_SCOPE_AGENT)), 1e-12f);
    float ascale = a_amax * (1.f / QMAX), ainv = QMAX / a_amax;
    const int b = tid >> 12;
    const int hw = (tid & 4095) << 2;
    const size_t base = (size_t)b * CIN * HW + hw;
    float h[CR][4];
    {
        float hacc[CR][4];
#pragma unroll
        for (int o = 0; o < CR; o++)
#pragma unroll
            for (int v = 0; v < 4; v++) hacc[o][v] = 0.f;
        const float* xb = x + base;
#pragma unroll
        for (int c = 0; c < CIN; c++) {
            float4 xv = *(const float4*)(xb + (size_t)c * HW);
            float q0 = fq(xv.x, ainv, ascale), q1 = fq(xv.y, ainv, ascale);
            float q2 = fq(xv.z, ainv, ascale), q3 = fq(xv.w, ainv, ascale);
#pragma unroll
            for (int o = 0; o < CR; o++) {
                float w = wqr[o * CIN + c];
                hacc[o][0] += q0 * w; hacc[o][1] += q1 * w;
                hacc[o][2] += q2 * w; hacc[o][3] += q3 * w;
            }
        }
        float m = 0.f;
#pragma unroll
        for (int o = 0; o < CR; o++) {
            float bb = bsh[o];
#pragma unroll
            for (int v = 0; v < 4; v++) {
                float hv = hacc[o][v] + bb;
                hv = hv * sigmoidf_(hv);
                h[o][v] = hv;
                m = fmaxf(m, fabsf(hv));
            }
        }
#pragma unroll
        for (int off = 32; off > 0; off >>= 1) m = fmaxf(m, __shfl_xor(m, off, 64));
        __syncthreads();                  // red[] reuse
        if ((t & 63) == 0) red[t >> 6] = m;
        __syncthreads();
        if (t == 0) {
            m = fmaxf(fmaxf(red[0], red[1]), fmaxf(red[2], red[3]));
            atomicMax(&wsu[1], __float_as_uint(m));
        }
    }
    grid_bar(&wsu[2], &wsu[3], COOP_BLOCKS);

    // ---- phase 3: quantize h in-register, expand conv, identity * sigmoid(g) ----
    float h_amax = fmaxf(__uint_as_float(
        __hip_atomic_load(&wsu[1], __ATOMIC_ACQUIRE, __HIP_MEMORY_SCOPE_AGENT)), 1e-12f);
    float hscale = h_amax * (1.f / QMAX), hinv = QMAX / h_amax;
#pragma unroll
    for (int o = 0; o < CR; o++)
#pragma unroll
        for (int v = 0; v < 4; v++) h[o][v] = fq(h[o][v], hinv, hscale);

#pragma unroll 4
    for (int o2 = 0; o2 < CIN; o2++) {
        float g0 = besh[o2], g1 = g0, g2 = g0, g3 = g0;
#pragma unroll
        for (int cr = 0; cr < CR; cr++) {
            float w = wqe[o2 * CR + cr];
            g0 += h[cr][0] * w; g1 += h[cr][1] * w;
            g2 += h[cr][2] * w; g3 += h[cr][3] * w;
        }
        size_t off = base + (size_t)o2 * HW;
        float4 idv = *(const float4*)(identity + off);
        float4 ov;
        ov.x = idv.x * sigmoidf_(g0);
        ov.y = idv.y * sigmoidf_(g1);
        ov.z = idv.z * sigmoidf_(g2);
        ov.w = idv.w * sigmoidf_(g3);
        *(float4*)(out + off) = ov;
    }
}

// ================= Fallback path (proven R2 kernels) =================
__global__ __launch_bounds__(256) void k1_xmax(const float4* __restrict__ x4,
                                               unsigned int* __restrict__ wsu) {
    int idx = blockIdx.x * 256 + threadIdx.x;
    float m = 0.f;
#pragma unroll
    for (int i = 0; i < 16; i++) {
        float4 v = x4[idx + i * 524288];
        m = fmaxf(m, fmaxf(fmaxf(fabsf(v.x), fabsf(v.y)), fmaxf(fabsf(v.z), fabsf(v.w))));
    }
#pragma unroll
    for (int off = 32; off > 0; off >>= 1) m = fmaxf(m, __shfl_xor(m, off, 64));
    __shared__ float red[4];
    int t = threadIdx.x;
    if ((t & 63) == 0) red[t >> 6] = m;
    __syncthreads();
    if (t == 0) {
        m = fmaxf(fmaxf(red[0], red[1]), fmaxf(red[2], red[3]));
        atomicMax(&wsu[0], __float_as_uint(m));
    }
}

__global__ __launch_bounds__(256) void k2_hmax(const float* __restrict__ x,
                                               const float* __restrict__ wr,
                                               const float* __restrict__ br,
                                               const unsigned int* __restrict__ wsu,
                                               unsigned int* __restrict__ hmax,
                                               float* __restrict__ hbuf) {
    __shared__ float wq[CR * CIN], bsh[CR], amr[CR];
    int t = threadIdx.x;
    if (t < CR) {
        float mm = 0.f;
        for (int c = 0; c < CIN; c++) mm = fmaxf(mm, fabsf(wr[t * CIN + c]));
        amr[t] = fmaxf(mm, 1e-12f);
        bsh[t] = br[t];
    }
    __syncthreads();
    {
        float amax = amr[t >> 5];
        wq[t] = fq(wr[t], QMAX / amax, amax * (1.f / QMAX));
    }
    __syncthreads();
    float a_amax = fmaxf(__uint_as_float(wsu[0]), 1e-12f);
    float scale = a_amax * (1.f / QMAX), inv_scale = QMAX / a_amax;
    int tid = blockIdx.x * 256 + t;
    int b = tid >> 12;
    int hw = (tid & 4095) << 2;
    const float* xb = x + (size_t)b * CIN * HW + hw;
    float hacc[CR][4];
#pragma unroll
    for (int o = 0; o < CR; o++)
#pragma unroll
        for (int v = 0; v < 4; v++) hacc[o][v] = 0.f;
#pragma unroll
    for (int c = 0; c < CIN; c++) {
        float4 xv = *(const float4*)(xb + (size_t)c * HW);
        float q0 = fq(xv.x, inv_scale, scale), q1 = fq(xv.y, inv_scale, scale);
        float q2 = fq(xv.z, inv_scale, scale), q3 = fq(xv.w, inv_scale, scale);
#pragma unroll
        for (int o = 0; o < CR; o++) {
            float w = wq[o * CIN + c];
            hacc[o][0] += q0 * w; hacc[o][1] += q1 * w;
            hacc[o][2] += q2 * w; hacc[o][3] += q3 * w;
        }
    }
    float m = 0.f;
#pragma unroll
    for (int o = 0; o < CR; o++) {
        float bb = bsh[o];
        float4 hv;
        float* hp = (float*)&hv;
#pragma unroll
        for (int v = 0; v < 4; v++) {
            float h = hacc[o][v] + bb;
            h = h * sigmoidf_(h);
            hp[v] = h;
            m = fmaxf(m, fabsf(h));
        }
        if (hbuf) *(float4*)(hbuf + ((size_t)(b * CR + o)) * HW + hw) = hv;
    }
#pragma unroll
    for (int off = 32; off > 0; off >>= 1) m = fmaxf(m, __shfl_xor(m, off, 64));
    __shared__ float red[4];
    if ((t & 63) == 0) red[t >> 6] = m;
    __syncthreads();
    if (t == 0) {
        m = fmaxf(fmaxf(red[0], red[1]), fmaxf(red[2], red[3]));
        atomicMax(hmax, __float_as_uint(m));
    }
}

__global__ __launch_bounds__(256) void k3_out(const float* __restrict__ hbuf,
                                              const float* __restrict__ identity,
                                              const float* __restrict__ we,
                                              const float* __restrict__ be,
                                              const unsigned int* __restrict__ wsu,
                                              float* __restrict__ out) {
    const int y = blockIdx.y;
    __shared__ float wqe[16 * CR], besh[16], ame[16];
    int t = threadIdx.x;
    if (t < 16) {
        int r = 16 * y + t;
        float mm = 0.f;
        for (int c = 0; c < CR; c++) mm = fmaxf(mm, fabsf(we[r * CR + c]));
        ame[t] = fmaxf(mm, 1e-12f);
        besh[t] = be[r];
    }
    __syncthreads();
    if (t < 128) {
        int r16 = t >> 3;
        float amax = ame[r16];
        wqe[t] = fq(we[(16 * y + r16) * CR + (t & 7)], QMAX / amax, amax * (1.f / QMAX));
    }
    __syncthreads();
    float h_amax = fmaxf(__uint_as_float(wsu[1]), 1e-12f);
    float hscale = h_amax * (1.f / QMAX), hinv = QMAX / h_amax;
    int tid = blockIdx.x * 256 + t;
    int b = tid >> 12;
    int hw = (tid & 4095) << 2;
    size_t base = (size_t)b * CIN * HW + hw;
    float hq[CR][4];
#pragma unroll
    for (int cr = 0; cr < CR; cr++) {
        float4 hv = *(const float4*)(hbuf + ((size_t)(b * CR + cr)) * HW + hw);
        hq[cr][0] = fq(hv.x, hinv, hscale);
        hq[cr][1] = fq(hv.y, hinv, hscale);
        hq[cr][2] = fq(hv.z, hinv, hscale);
        hq[cr][3] = fq(hv.w, hinv, hscale);
    }
#pragma unroll 4
    for (int o = 0; o < 16; o++) {
        float g0 = besh[o], g1 = g0, g2 = g0, g3 = g0;
#pragma unroll
        for (int cr = 0; cr < CR; cr++) {
            float w = wqe[o * CR + cr];
            g0 += hq[cr][0] * w; g1 += hq[cr][1] * w;
            g2 += hq[cr][2] * w; g3 += hq[cr][3] * w;
        }
        size_t off = base + (size_t)(16 * y + o) * HW;
        float4 idv = *(const float4*)(identity + off);
        float4 ov;
        ov.x = idv.x * sigmoidf_(g0);
        ov.y = idv.y * sigmoidf_(g1);
        ov.z = idv.z * sigmoidf_(g2);
        ov.w = idv.w * sigmoidf_(g3);
        *(float4*)(out + off) = ov;
    }
}

__global__ __launch_bounds__(256) void k3_out_rc(const float* __restrict__ x,
                                                 const float* __restrict__ identity,
                                                 const float* __restrict__ wr,
                                                 const float* __restrict__ br,
                                                 const float* __restrict__ we,
                                                 const float* __restrict__ be,
                                                 const unsigned int* __restrict__ wsu,
                                                 float* __restrict__ out) {
    __shared__ float wqr[CR * CIN], wqe[CIN * CR], bsh[CR], besh[CIN], amr[CR], ame[CIN];
    int t = threadIdx.x;
    if (t < CR) {
        float mm = 0.f;
        for (int c = 0; c < CIN; c++) mm = fmaxf(mm, fabsf(wr[t * CIN + c]));
        amr[t] = fmaxf(mm, 1e-12f);
        bsh[t] = br[t];
    }
    if (t >= 64 && t < 64 + CIN) {
        int r = t - 64;
        float mm = 0.f;
        for (int c = 0; c < CR; c++) mm = fmaxf(mm, fabsf(we[r * CR + c]));
        ame[r] = fmaxf(mm, 1e-12f);
        besh[r] = be[r];
    }
    __syncthreads();
    {
        float amax = amr[t >> 5];
        wqr[t] = fq(wr[t], QMAX / amax, amax * (1.f / QMAX));
        float amax2 = ame[t >> 3];
        wqe[t] = fq(we[t], QMAX / amax2, amax2 * (1.f / QMAX));
    }
    __syncthreads();
    float a_amax = fmaxf(__uint_as_float(wsu[0]), 1e-12f);
    float ascale = a_amax * (1.f / QMAX), ainv = QMAX / a_amax;
    float h_amax = fmaxf(__uint_as_float(wsu[1]), 1e-12f);
    float hscale = h_amax * (1.f / QMAX), hinv = QMAX / h_amax;
    int tid = blockIdx.x * 256 + t;
    int b = tid >> 12;
    int hw = (tid & 4095) << 2;
    size_t base = (size_t)b * CIN * HW + hw;
    const float* xb = x + base;
    float hq[CR][4];
    {
        float hacc[CR][4];
#pragma unroll
        for (int o = 0; o < CR; o++)
#pragma unroll
            for (int v = 0; v < 4; v++) hacc[o][v] = 0.f;
#pragma unroll
        for (int c = 0; c < CIN; c++) {
            float4 xv = *(const float4*)(xb + (size_t)c * HW);
            float q0 = fq(xv.x, ainv, ascale), q1 = fq(xv.y, ainv, ascale);
            float q2 = fq(xv.z, ainv, ascale), q3 = fq(xv.w, ainv, ascale);
#pragma unroll
            for (int o = 0; o < CR; o++) {
                float w = wqr[o * CIN + c];
                hacc[o][0] += q0 * w; hacc[o][1] += q1 * w;
                hacc[o][2] += q2 * w; hacc[o][3] += q3 * w;
            }
        }
#pragma unroll
        for (int o = 0; o < CR; o++) {
            float bb = bsh[o];
#pragma unroll
            for (int v = 0; v < 4; v++) {
                float h = hacc[o][v] + bb;
                h = h * sigmoidf_(h);
                hq[o][v] = fq(h, hinv, hscale);
            }
        }
    }
#pragma unroll 4
    for (int o2 = 0; o2 < CIN; o2++) {
        float g0 = besh[o2], g1 = g0, g2 = g0, g3 = g0;
#pragma unroll
        for (int cr = 0; cr < CR; cr++) {
            float w = wqe[o2 * CR + cr];
            g0 += hq[cr][0] * w; g1 += hq[cr][1] * w;
            g2 += hq[cr][2] * w; g3 += hq[cr][3] * w;
        }
        size_t off = base + (size_t)o2 * HW;
        float4 idv = *(const float4*)(identity + off);
        float4 ov;
        ov.x = idv.x * sigmoidf_(g0);
        ov.y = idv.y * sigmoidf_(g1);
        ov.z = idv.z * sigmoidf_(g2);
        ov.w = idv.w * sigmoidf_(g3);
        *(float4*)(out + off) = ov;
    }
}

extern "C" void kernel_launch(void* const* d_in, const int* in_sizes, int n_in,
                              void* d_out, int out_size, void* d_ws, size_t ws_size,
                              hipStream_t stream) {
    const float* x        = (const float*)d_in[0];
    const float* identity = (const float*)d_in[1];
    const float* wr       = (const float*)d_in[2];
    const float* br       = (const float*)d_in[3];
    const float* we       = (const float*)d_in[4];
    const float* be       = (const float*)d_in[5];
    float* out            = (float*)d_out;
    float* wsf            = (float*)d_ws;
    unsigned int* wsu     = (unsigned int*)d_ws;

    hipMemsetAsync(d_ws, 0, 16, stream);   // zero amax accumulators + barrier cnt/gen

    // Try the fused cooperative kernel (needs 4 blocks/CU co-residency).
    int maxb = 0;
    hipError_t qerr = hipOccupancyMaxActiveBlocksPerMultiprocessor(&maxb, se_fused, 256, 0);
    bool coop_ok = false;
    if (qerr == hipSuccess && maxb >= 4) {
        void* args[] = {(void*)&x, (void*)&identity, (void*)&wr, (void*)&br,
                        (void*)&we, (void*)&be, (void*)&wsu, (void*)&out};
        hipError_t lerr = hipLaunchCooperativeKernel((void*)se_fused, dim3(COOP_BLOCKS),
                                                     dim3(256), args, 0, stream);
        coop_ok = (lerr == hipSuccess);
    }
    if (coop_ok) return;

    // Fallback: proven 3-kernel path.
    const bool big_ws = (ws_size >= WS_NEEDED);
    float* hbuf = big_ws ? (wsf + H_OFF) : nullptr;
    hipLaunchKernelGGL(k1_xmax, dim3(2048), dim3(256), 0, stream, (const float4*)x, wsu);
    hipLaunchKernelGGL(k2_hmax, dim3(NQUAD / 256), dim3(256), 0, stream,
                       x, wr, br, wsu, &wsu[1], hbuf);
    if (big_ws) {
        hipLaunchKernelGGL(k3_out, dim3(NQUAD / 256, 2), dim3(256), 0, stream,
                           hbuf, identity, we, be, wsu, out);
    } else {
        hipLaunchKernelGGL(k3_out_rc, dim3(NQUAD / 256), dim3(256), 0, stream,
                           x, identity, wr, br, we, be, wsu, out);
    }
}

// Round 2
// 371.556 us; speedup vs baseline: 1.0089x; 1.0089x over previous
//
#include <hip/hip_runtime.h>
#include <math.h>

#define QMAX 127.0f
#define CIN 32
#define CR 8
#define HW 16384                 // 128*128
#define BATCH 64
#define NPIX (BATCH*HW)          // 1,048,576 pixels
#define NQUAD (NPIX/4)           // 262,144 pixel-quads
#define NX (BATCH*CIN*HW)        // 33,554,432 x elements
#define COOP_BLOCKS (NQUAD/256)  // 1024 blocks -> exactly 1 quad per thread

// ws layout: wsu[0]=amax_x bits, wsu[1]=amax_h bits, wsu[2]=barrier count, wsu[3]=barrier gen;
// h buffer (fallback only) at wsf+64
#define H_OFF 64
#define WS_NEEDED ((size_t)(H_OFF + (size_t)NPIX * CR) * 4)

__device__ __forceinline__ float fq(float v, float inv_scale, float scale) {
    return rintf(fminf(fmaxf(v * inv_scale, -QMAX), QMAX)) * scale;  // round-half-even
}
__device__ __forceinline__ float sigmoidf_(float v) {
    return __builtin_amdgcn_rcpf(1.0f + __expf(-v));   // v_rcp_f32: ~1ulp, fine vs 5.5e-2 thr
}

// Minimal grid barrier: agent-scope atomics only, NO cache flush/invalidate.
// Safe here because the only cross-block data (wsu[0], wsu[1]) are themselves
// device-scope atomics; h stays in registers across the barrier.
// Requires all blocks co-resident (guaranteed: 1024 blocks, 4/CU by launch_bounds,
// checked via occupancy query before launch). cnt/gen zeroed by the 16-B memset.
__device__ __forceinline__ void grid_bar(unsigned int* __restrict__ cnt,
                                         unsigned int* __restrict__ gen,
                                         unsigned int nb) {
    __syncthreads();
    if (threadIdx.x == 0) {
        // ACQUIRE: the gen read must not sink below the arrival fetch_add.
        unsigned int g = __hip_atomic_load(gen, __ATOMIC_ACQUIRE, __HIP_MEMORY_SCOPE_AGENT);
        unsigned int a = __hip_atomic_fetch_add(cnt, 1u, __ATOMIC_ACQ_REL, __HIP_MEMORY_SCOPE_AGENT);
        if (a == nb - 1u) {
            __hip_atomic_store(cnt, 0u, __ATOMIC_RELAXED, __HIP_MEMORY_SCOPE_AGENT);
            __hip_atomic_fetch_add(gen, 1u, __ATOMIC_RELEASE, __HIP_MEMORY_SCOPE_AGENT);
        } else {
            while (__hip_atomic_load(gen, __ATOMIC_RELAXED, __HIP_MEMORY_SCOPE_AGENT) == g)
                __builtin_amdgcn_s_sleep(1);
            __builtin_amdgcn_fence(__ATOMIC_ACQUIRE, "agent");
        }
    }
    __syncthreads();
}

// ================= Fused kernel (plain launch, graph-capturable) =================
// grid = 1024 blocks x 256 thr; __launch_bounds__(256,4) caps VGPR<=128 -> 4 blocks/CU.
__global__ __launch_bounds__(256, 4) void se_fused(const float* __restrict__ x,
                                                   const float* __restrict__ identity,
                                                   const float* __restrict__ wr,
                                                   const float* __restrict__ br,
                                                   const float* __restrict__ we,
                                                   const float* __restrict__ be,
                                                   unsigned int* __restrict__ wsu,
                                                   float* __restrict__ out) {
    int t = threadIdx.x;
    __shared__ float wqr[CR * CIN], wqe[CIN * CR], bsh[CR], besh[CIN], amr[CR], ame[CIN];
    __shared__ float red[4];

    // ---- weight quantization (per-block, tiny) ----
    if (t < CR) {
        float mm = 0.f;
        for (int c = 0; c < CIN; c++) mm = fmaxf(mm, fabsf(wr[t * CIN + c]));
        amr[t] = fmaxf(mm, 1e-12f);
        bsh[t] = br[t];
    }
    if (t >= 64 && t < 64 + CIN) {
        int r = t - 64;
        float mm = 0.f;
        for (int c = 0; c < CR; c++) mm = fmaxf(mm, fabsf(we[r * CR + c]));
        ame[r] = fmaxf(mm, 1e-12f);
        besh[r] = be[r];
    }
    __syncthreads();
    {
        float a1 = amr[t >> 5];
        wqr[t] = fq(wr[t], QMAX / a1, a1 * (1.f / QMAX));
        float a2 = ame[t >> 3];
        wqe[t] = fq(we[t], QMAX / a2, a2 * (1.f / QMAX));
    }
    __syncthreads();

    const int tid = blockIdx.x * 256 + t;

    // ---- phase 1: global max|x| (32 float4 per thread, grid covers NX exactly) ----
    {
        const float4* x4 = (const float4*)x;
        float m = 0.f;
#pragma unroll 8
        for (int i = 0; i < 32; i++) {
            float4 v = x4[tid + i * NQUAD];
            m = fmaxf(m, fmaxf(fmaxf(fabsf(v.x), fabsf(v.y)), fmaxf(fabsf(v.z), fabsf(v.w))));
        }
#pragma unroll
        for (int off = 32; off > 0; off >>= 1) m = fmaxf(m, __shfl_xor(m, off, 64));
        if ((t & 63) == 0) red[t >> 6] = m;
        __syncthreads();
        if (t == 0) {
            m = fmaxf(fmaxf(red[0], red[1]), fmaxf(red[2], red[3]));
            atomicMax(&wsu[0], __float_as_uint(m));   // values >=0: uint order == float order
        }
    }
    grid_bar(&wsu[2], &wsu[3], COOP_BLOCKS);

    // ---- phase 2: h = SiLU(conv_reduce(quant(x))) kept in registers; global max|h| ----
    float a_amax = fmaxf(__uint_as_float(
        __hip_atomic_load(&wsu[0], __ATOMIC_ACQUIRE, __HIP_MEMORY_SCOPE_AGENT)), 1e-12f);
    float ascale = a_amax * (1.f / QMAX), ainv = QMAX / a_amax;
    const int b = tid >> 12;
    const int hw = (tid & 4095) << 2;
    const size_t base = (size_t)b * CIN * HW + hw;
    float h[CR][4];
    {
        float hacc[CR][4];
#pragma unroll
        for (int o = 0; o < CR; o++)
#pragma unroll
            for (int v = 0; v < 4; v++) hacc[o][v] = 0.f;
        const float* xb = x + base;
        // load-8 / compute-8 staging: keep 8 x-loads in flight per wave
        for (int cg_ = 0; cg_ < CIN / 8; cg_++) {
            float4 xv[8];
#pragma unroll
            for (int j = 0; j < 8; j++)
                xv[j] = *(const float4*)(xb + (size_t)(cg_ * 8 + j) * HW);
#pragma unroll
            for (int j = 0; j < 8; j++) {
                int c = cg_ * 8 + j;
                float q0 = fq(xv[j].x, ainv, ascale), q1 = fq(xv[j].y, ainv, ascale);
                float q2 = fq(xv[j].z, ainv, ascale), q3 = fq(xv[j].w, ainv, ascale);
#pragma unroll
                for (int o = 0; o < CR; o++) {
                    float w = wqr[o * CIN + c];
                    hacc[o][0] += q0 * w; hacc[o][1] += q1 * w;
                    hacc[o][2] += q2 * w; hacc[o][3] += q3 * w;
                }
            }
        }
        float m = 0.f;
#pragma unroll
        for (int o = 0; o < CR; o++) {
            float bb = bsh[o];
#pragma unroll
            for (int v = 0; v < 4; v++) {
                float hv = hacc[o][v] + bb;
                hv = hv * sigmoidf_(hv);
                h[o][v] = hv;
                m = fmaxf(m, fabsf(hv));
            }
        }
#pragma unroll
        for (int off = 32; off > 0; off >>= 1) m = fmaxf(m, __shfl_xor(m, off, 64));
        __syncthreads();                  // red[] reuse
        if ((t & 63) == 0) red[t >> 6] = m;
        __syncthreads();
        if (t == 0) {
            m = fmaxf(fmaxf(red[0], red[1]), fmaxf(red[2], red[3]));
            atomicMax(&wsu[1], __float_as_uint(m));
        }
    }
    grid_bar(&wsu[2], &wsu[3], COOP_BLOCKS);

    // ---- phase 3: quantize h in-register, expand conv, identity * sigmoid(g) ----
    float h_amax = fmaxf(__uint_as_float(
        __hip_atomic_load(&wsu[1], __ATOMIC_ACQUIRE, __HIP_MEMORY_SCOPE_AGENT)), 1e-12f);
    float hscale = h_amax * (1.f / QMAX), hinv = QMAX / h_amax;
#pragma unroll
    for (int o = 0; o < CR; o++)
#pragma unroll
        for (int v = 0; v < 4; v++) h[o][v] = fq(h[o][v], hinv, hscale);

    // load-8 / compute-8 staging on identity; stores pipeline behind loads
    for (int og = 0; og < CIN / 8; og++) {
        float4 idv[8];
#pragma unroll
        for (int j = 0; j < 8; j++)
            idv[j] = *(const float4*)(identity + base + (size_t)(og * 8 + j) * HW);
#pragma unroll
        for (int j = 0; j < 8; j++) {
            int o2 = og * 8 + j;
            float g0 = besh[o2], g1 = g0, g2 = g0, g3 = g0;
#pragma unroll
            for (int cr = 0; cr < CR; cr++) {
                float w = wqe[o2 * CR + cr];
                g0 += h[cr][0] * w; g1 += h[cr][1] * w;
                g2 += h[cr][2] * w; g3 += h[cr][3] * w;
            }
            size_t off = base + (size_t)o2 * HW;
            float4 ov;
            ov.x = idv[j].x * sigmoidf_(g0);
            ov.y = idv[j].y * sigmoidf_(g1);
            ov.z = idv[j].z * sigmoidf_(g2);
            ov.w = idv[j].w * sigmoidf_(g3);
            *(float4*)(out + off) = ov;
        }
    }
}

// ================= Fallback path (proven R2 kernels) =================
__global__ __launch_bounds__(256) void k1_xmax(const float4* __restrict__ x4,
                                               unsigned int* __restrict__ wsu) {
    int idx = blockIdx.x * 256 + threadIdx.x;
    float m = 0.f;
#pragma unroll
    for (int i = 0; i < 16; i++) {
        float4 v = x4[idx + i * 524288];
        m = fmaxf(m, fmaxf(fmaxf(fabsf(v.x), fabsf(v.y)), fmaxf(fabsf(v.z), fabsf(v.w))));
    }
#pragma unroll
    for (int off = 32; off > 0; off >>= 1) m = fmaxf(m, __shfl_xor(m, off, 64));
    __shared__ float red[4];
    int t = threadIdx.x;
    if ((t & 63) == 0) red[t >> 6] = m;
    __syncthreads();
    if (t == 0) {
        m = fmaxf(fmaxf(red[0], red[1]), fmaxf(red[2], red[3]));
        atomicMax(&wsu[0], __float_as_uint(m));
    }
}

__global__ __launch_bounds__(256) void k2_hmax(const float* __restrict__ x,
                                               const float* __restrict__ wr,
                                               const float* __restrict__ br,
                                               const unsigned int* __restrict__ wsu,
                                               unsigned int* __restrict__ hmax,
                                               float* __restrict__ hbuf) {
    __shared__ float wq[CR * CIN], bsh[CR], amr[CR];
    int t = threadIdx.x;
    if (t < CR) {
        float mm = 0.f;
        for (int c = 0; c < CIN; c++) mm = fmaxf(mm, fabsf(wr[t * CIN + c]));
        amr[t] = fmaxf(mm, 1e-12f);
        bsh[t] = br[t];
    }
    __syncthreads();
    {
        float amax = amr[t >> 5];
        wq[t] = fq(wr[t], QMAX / amax, amax * (1.f / QMAX));
    }
    __syncthreads();
    float a_amax = fmaxf(__uint_as_float(wsu[0]), 1e-12f);
    float scale = a_amax * (1.f / QMAX), inv_scale = QMAX / a_amax;
    int tid = blockIdx.x * 256 + t;
    int b = tid >> 12;
    int hw = (tid & 4095) << 2;
    const float* xb = x + (size_t)b * CIN * HW + hw;
    float hacc[CR][4];
#pragma unroll
    for (int o = 0; o < CR; o++)
#pragma unroll
        for (int v = 0; v < 4; v++) hacc[o][v] = 0.f;
#pragma unroll
    for (int c = 0; c < CIN; c++) {
        float4 xv = *(const float4*)(xb + (size_t)c * HW);
        float q0 = fq(xv.x, inv_scale, scale), q1 = fq(xv.y, inv_scale, scale);
        float q2 = fq(xv.z, inv_scale, scale), q3 = fq(xv.w, inv_scale, scale);
#pragma unroll
        for (int o = 0; o < CR; o++) {
            float w = wq[o * CIN + c];
            hacc[o][0] += q0 * w; hacc[o][1] += q1 * w;
            hacc[o][2] += q2 * w; hacc[o][3] += q3 * w;
        }
    }
    float m = 0.f;
#pragma unroll
    for (int o = 0; o < CR; o++) {
        float bb = bsh[o];
        float4 hv;
        float* hp = (float*)&hv;
#pragma unroll
        for (int v = 0; v < 4; v++) {
            float h = hacc[o][v] + bb;
            h = h * sigmoidf_(h);
            hp[v] = h;
            m = fmaxf(m, fabsf(h));
        }
        if (hbuf) *(float4*)(hbuf + ((size_t)(b * CR + o)) * HW + hw) = hv;
    }
#pragma unroll
    for (int off = 32; off > 0; off >>= 1) m = fmaxf(m, __shfl_xor(m, off, 64));
    __shared__ float red[4];
    if ((t & 63) == 0) red[t >> 6] = m;
    __syncthreads();
    if (t == 0) {
        m = fmaxf(fmaxf(red[0], red[1]), fmaxf(red[2], red[3]));
        atomicMax(hmax, __float_as_uint(m));
    }
}

__global__ __launch_bounds__(256) void k3_out(const float* __restrict__ hbuf,
                                              const float* __restrict__ identity,
                                              const float* __restrict__ we,
                                              const float* __restrict__ be,
                                              const unsigned int* __restrict__ wsu,
                                              float* __restrict__ out) {
    const int y = blockIdx.y;
    __shared__ float wqe[16 * CR], besh[16], ame[16];
    int t = threadIdx.x;
    if (t < 16) {
        int r = 16 * y + t;
        float mm = 0.f;
        for (int c = 0; c < CR; c++) mm = fmaxf(mm, fabsf(we[r * CR + c]));
        ame[t] = fmaxf(mm, 1e-12f);
        besh[t] = be[r];
    }
    __syncthreads();
    if (t < 128) {
        int r16 = t >> 3;
        float amax = ame[r16];
        wqe[t] = fq(we[(16 * y + r16) * CR + (t & 7)], QMAX / amax, amax * (1.f / QMAX));
    }
    __syncthreads();
    float h_amax = fmaxf(__uint_as_float(wsu[1]), 1e-12f);
    float hscale = h_amax * (1.f / QMAX), hinv = QMAX / h_amax;
    int tid = blockIdx.x * 256 + t;
    int b = tid >> 12;
    int hw = (tid & 4095) << 2;
    size_t base = (size_t)b * CIN * HW + hw;
    float hq[CR][4];
#pragma unroll
    for (int cr = 0; cr < CR; cr++) {
        float4 hv = *(const float4*)(hbuf + ((size_t)(b * CR + cr)) * HW + hw);
        hq[cr][0] = fq(hv.x, hinv, hscale);
        hq[cr][1] = fq(hv.y, hinv, hscale);
        hq[cr][2] = fq(hv.z, hinv, hscale);
        hq[cr][3] = fq(hv.w, hinv, hscale);
    }
#pragma unroll 4
    for (int o = 0; o < 16; o++) {
        float g0 = besh[o], g1 = g0, g2 = g0, g3 = g0;
#pragma unroll
        for (int cr = 0; cr < CR; cr++) {
            float w = wqe[o * CR + cr];
            g0 += hq[cr][0] * w; g1 += hq[cr][1] * w;
            g2 += hq[cr][2] * w; g3 += hq[cr][3] * w;
        }
        size_t off = base + (size_t)(16 * y + o) * HW;
        float4 idv = *(const float4*)(identity + off);
        float4 ov;
        ov.x = idv.x * sigmoidf_(g0);
        ov.y = idv.y * sigmoidf_(g1);
        ov.z = idv.z * sigmoidf_(g2);
        ov.w = idv.w * sigmoidf_(g3);
        *(float4*)(out + off) = ov;
    }
}

__global__ __launch_bounds__(256) void k3_out_rc(const float* __restrict__ x,
                                                 const float* __restrict__ identity,
                                                 const float* __restrict__ wr,
                                                 const float* __restrict__ br,
                                                 const float* __restrict__ we,
                                                 const float* __restrict__ be,
                                                 const unsigned int* __restrict__ wsu,
                                                 float* __restrict__ out) {
    __shared__ float wqr[CR * CIN], wqe[CIN * CR], bsh[CR], besh[CIN], amr[CR], ame[CIN];
    int t = threadIdx.x;
    if (t < CR) {
        float mm = 0.f;
        for (int c = 0; c < CIN; c++) mm = fmaxf(mm, fabsf(wr[t * CIN + c]));
        amr[t] = fmaxf(mm, 1e-12f);
        bsh[t] = br[t];
    }
    if (t >= 64 && t < 64 + CIN) {
        int r = t - 64;
        float mm = 0.f;
        for (int c = 0; c < CR; c++) mm = fmaxf(mm, fabsf(we[r * CR + c]));
        ame[r] = fmaxf(mm, 1e-12f);
        besh[r] = be[r];
    }
    __syncthreads();
    {
        float amax = amr[t >> 5];
        wqr[t] = fq(wr[t], QMAX / amax, amax * (1.f / QMAX));
        float amax2 = ame[t >> 3];
        wqe[t] = fq(we[t], QMAX / amax2, amax2 * (1.f / QMAX));
    }
    __syncthreads();
    float a_amax = fmaxf(__uint_as_float(wsu[0]), 1e-12f);
    float ascale = a_amax * (1.f / QMAX), ainv = QMAX / a_amax;
    float h_amax = fmaxf(__uint_as_float(wsu[1]), 1e-12f);
    float hscale = h_amax * (1.f / QMAX), hinv = QMAX / h_amax;
    int tid = blockIdx.x * 256 + t;
    int b = tid >> 12;
    int hw = (tid & 4095) << 2;
    size_t base = (size_t)b * CIN * HW + hw;
    const float* xb = x + base;
    float hq[CR][4];
    {
        float hacc[CR][4];
#pragma unroll
        for (int o = 0; o < CR; o++)
#pragma unroll
            for (int v = 0; v < 4; v++) hacc[o][v] = 0.f;
#pragma unroll
        for (int c = 0; c < CIN; c++) {
            float4 xv = *(const float4*)(xb + (size_t)c * HW);
            float q0 = fq(xv.x, ainv, ascale), q1 = fq(xv.y, ainv, ascale);
            float q2 = fq(xv.z, ainv, ascale), q3 = fq(xv.w, ainv, ascale);
#pragma unroll
            for (int o = 0; o < CR; o++) {
                float w = wqr[o * CIN + c];
                hacc[o][0] += q0 * w; hacc[o][1] += q1 * w;
                hacc[o][2] += q2 * w; hacc[o][3] += q3 * w;
            }
        }
#pragma unroll
        for (int o = 0; o < CR; o++) {
            float bb = bsh[o];
#pragma unroll
            for (int v = 0; v < 4; v++) {
                float h = hacc[o][v] + bb;
                h = h * sigmoidf_(h);
                hq[o][v] = fq(h, hinv, hscale);
            }
        }
    }
#pragma unroll 4
    for (int o2 = 0; o2 < CIN; o2++) {
        float g0 = besh[o2], g1 = g0, g2 = g0, g3 = g0;
#pragma unroll
        for (int cr = 0; cr < CR; cr++) {
            float w = wqe[o2 * CR + cr];
            g0 += hq[cr][0] * w; g1 += hq[cr][1] * w;
            g2 += hq[cr][2] * w; g3 += hq[cr][3] * w;
        }
        size_t off = base + (size_t)o2 * HW;
        float4 idv = *(const float4*)(identity + off);
        float4 ov;
        ov.x = idv.x * sigmoidf_(g0);
        ov.y = idv.y * sigmoidf_(g1);
        ov.z = idv.z * sigmoidf_(g2);
        ov.w = idv.w * sigmoidf_(g3);
        *(float4*)(out + off) = ov;
    }
}

extern "C" void kernel_launch(void* const* d_in, const int* in_sizes, int n_in,
                              void* d_out, int out_size, void* d_ws, size_t ws_size,
                              hipStream_t stream) {
    const float* x        = (const float*)d_in[0];
    const float* identity = (const float*)d_in[1];
    const float* wr       = (const float*)d_in[2];
    const float* br       = (const float*)d_in[3];
    const float* we       = (const float*)d_in[4];
    const float* be       = (const float*)d_in[5];
    float* out            = (float*)d_out;
    float* wsf            = (float*)d_ws;
    unsigned int* wsu     = (unsigned int*)d_ws;

    hipMemsetAsync(d_ws, 0, 16, stream);   // zero amax accumulators + barrier cnt/gen

    // Plain (graph-capturable) launch of the fused kernel. Co-residency of all
    // 1024 blocks is required by the spin barrier; guaranteed when >=4 blocks/CU fit.
    int maxb = 0;
    hipError_t qerr = hipOccupancyMaxActiveBlocksPerMultiprocessor(&maxb, se_fused, 256, 0);
    if (qerr == hipSuccess && maxb >= 4) {
        hipLaunchKernelGGL(se_fused, dim3(COOP_BLOCKS), dim3(256), 0, stream,
                           x, identity, wr, br, we, be, wsu, out);
        return;
    }

    // Fallback: proven 3-kernel path.
    const bool big_ws = (ws_size >= WS_NEEDED);
    float* hbuf = big_ws ? (wsf + H_OFF) : nullptr;
    hipLaunchKernelGGL(k1_xmax, dim3(2048), dim3(256), 0, stream, (const float4*)x, wsu);
    hipLaunchKernelGGL(k2_hmax, dim3(NQUAD / 256), dim3(256), 0, stream,
                       x, wr, br, wsu, &wsu[1], hbuf);
    if (big_ws) {
        hipLaunchKernelGGL(k3_out, dim3(NQUAD / 256, 2), dim3(256), 0, stream,
                           hbuf, identity, we, be, wsu, out);
    } else {
        hipLaunchKernelGGL(k3_out_rc, dim3(NQUAD / 256), dim3(256), 0, stream,
                           x, identity, wr, br, we, be, wsu, out);
    }
}